// Round 6
// baseline (16.347 us; speedup 1.0000x reference)
//
#include <hip/hip_runtime.h>
#include <math.h>

#define NBBINS 50
#define NWAVES 4
#define QCAP   516   // per-wave queue capacity: 512 possible passes + pad

#define TWO_PI_F 6.28318530717958647692f

// -------- Kernel 1: per-disk_a density, cheap-test compaction ----------------
// Exactness of the cheap test: disjoint branch has nd = 2d - 2r1 - 2r2 + 3, so
// nd < 6.6  <=>  d_norm < 1.8 + r1 + r2 = 1.8 + arn + brn. Overlap/containment
// branches have nd <= 3 and d <= r1+r2, always inside. Margin 1.85 absorbs
// rounding; boundary pairs contribute exp2(-59) ~ 2e-18 (invisible in fp32).
__global__ __launch_bounds__(256) void pcf_density_kernel(
    const float* __restrict__ A, const float* __restrict__ B,
    const int* __restrict__ flagp, float* __restrict__ density,
    int na, int nb_in, float rmax, float inv_rmax, float gf)
{
    const int i    = blockIdx.x;
    const int tid  = threadIdx.x;
    const int wave = tid >> 6;
    const int lane = tid & 63;
    const int flag = flagp[0];                 // same_category (device-read)
    const float* __restrict__ Bp = flag ? A : B;
    const int nb = flag ? na : nb_in;          // loop count; division stays nb_in

    __shared__ float2 q[NWAVES * QCAP];        // (d2, brn) per passing pair
    __shared__ float  part[NWAVES][NBBINS];
    __shared__ float  sarc[8];

    const float ax  = A[3*i+0];
    const float ay  = A[3*i+1];
    const float arn = A[3*i+2] * inv_rmax;

    // per-disk atan2 constants (8 total) — hoisted so wave 0's transcendentals
    // overlap everyone's B-load latency
    if (tid < 8) {
        const int b = tid >> 1;
        const float dxe = (b==0) ? ax : (b==1) ? (1.f-ax) : (b==2) ? ay : (1.f-ay);
        const float dyb = (b < 2) ? ay : ax;
        const float dye = (tid & 1) ? (1.f - dyb) : dyb;
        sarc[tid] = atan2f(dye, dxe);
    }

    // ---- phase 1: cheap d^2 test over this wave's j-chunk, compact survivors
    const int nbw   = (nb + NWAVES - 1) / NWAVES;
    const int j0    = wave * nbw;
    const int j1    = min(j0 + nbw, nb);
    const int iters = (j1 - j0 + 63) >> 6;
    const int qbase = wave * QCAP;
    int nq = 0;

    for (int it = 0; it < iters; ++it) {
        const int j = j0 + it*64 + lane;
        const bool valid = (j < j1) && !(flag && j == i);
        float d2  = 3.0e38f;
        float brn = 0.f;
        if (valid) {
            const float bx = Bp[3*j+0];
            const float by = Bp[3*j+1];
            brn = Bp[3*j+2] * inv_rmax;
            const float dx = ax - bx, dy = ay - by;
            d2 = dx*dx + dy*dy;                 // same expression as reference path
        }
        const float thr = (1.85f + arn + brn) * rmax;   // unnormalized radius bound
        const bool pass = (d2 < thr * thr);
        const unsigned long long m = __ballot(pass);
        if (pass) {
            const int pos = __popcll(m & ((1ull << lane) - 1ull));
            q[qbase + nq + pos] = make_float2(d2, brn);
        }
        nq += (int)__popcll(m);
    }

    // ---- phase 2: lane l owns bin l; full nd + gaussian only for survivors.
    // LDS reads are same-address across the wave -> broadcast, no conflicts.
    // nd is recomputed identically on all lanes (VALU-parallel, free).
    const float rsn = 0.1f * (float)(lane + 1);    // rs/RMAX for bin 'lane'
    float acc = 0.f;
    for (int u = 0; u < nq; ++u) {
        const float2 e = q[qbase + u];
        const float d  = sqrtf(e.x) * inv_rmax;
        const float r1 = fmaxf(arn, e.y);
        const float r2 = fminf(arn, e.y);
        const float extent  = fmaxf(d + r1 + r2, 2.0f*r1);
        const float overlap = fminf(fmaxf(r1 + r2 - d, 0.0f), 2.0f*r2);
        const float f = extent - overlap + d + r1 - r2;
        float nd = f - 4.0f*r1 - 2.0f*r2 + 3.0f;       // disjoint (common)
        if (d <= r1 + r2) {                            // rare: contact/containment
            nd = (d <= r1 - r2)
               ? f / (4.0f*r1 - 4.0f*r2 + 1e-8f)
               : (f - 4.0f*r1 + 7.0f*r2) / (3.0f*r2 + 1e-8f);
        }
        const float x = rsn - nd;
        acc += exp2f(-23.083120654223414f * (x * x));  // exp(-16 x^2)
    }
    if (lane < NBBINS) part[wave][lane] = acc;
    __syncthreads();

    // ---- epilogue: perimeter weight + area, write density[k][i] (transposed)
    if (tid < NBBINS) {
        const int k = tid;
        const float h = (part[0][k] + part[1][k] + part[2][k] + part[3][k]) * gf;

        const float rs = 0.1f*(float)(k+1) * rmax;
        float full = TWO_PI_F;
        #pragma unroll
        for (int b = 0; b < 4; ++b) {
            const float dxe = (b==0) ? ax : (b==1) ? (1.f-ax) : (b==2) ? ay : (1.f-ay);
            if (rs > dxe) {
                const float ratio = fminf(fmaxf(dxe / rs, -1.f), 1.f);
                const float alpha = acosf(ratio);
                full -= fminf(alpha, sarc[2*b]) + fminf(alpha, sarc[2*b+1]);
            }
        }
        float perim = full * (1.0f / TWO_PI_F);
        perim = fminf(fmaxf(perim, 0.f), 1.f);
        const float w = (perim > 1e-4f) ? (1.f / perim) : 0.f;

        const float inner = fmaxf(0.f, rs - 0.5f*rmax);
        const float outer = rs + 0.5f*rmax;
        const float area  = 3.14159265358979323846f * (outer*outer - inner*inner);

        density[k*na + i] = w * h / area / (float)nb_in;
    }
}

// -------- Kernel 2: mean/min/max over disks_a per bin (coalesced reads) ------
__global__ __launch_bounds__(256) void pcf_reduce_kernel(
    const float* __restrict__ density, float* __restrict__ out, int na)
{
    const int k   = blockIdx.x;
    const int tid = threadIdx.x;
    float s = 0.f, mn = 3.0e38f, mx = -3.0e38f;
    // unroll 4: issues the 4 independent L2/L3 loads in one latency exposure;
    // sequential add order is preserved (no fast-math) -> bit-exact result
    #pragma unroll 4
    for (int i = tid; i < na; i += 256) {
        const float v = density[k*na + i];
        s += v; mn = fminf(mn, v); mx = fmaxf(mx, v);
    }
    #pragma unroll
    for (int off = 32; off > 0; off >>= 1) {
        s  += __shfl_xor(s, off, 64);
        mn  = fminf(mn, __shfl_xor(mn, off, 64));
        mx  = fmaxf(mx, __shfl_xor(mx, off, 64));
    }
    __shared__ float ps[4], pmn[4], pmx[4];
    const int wave = tid >> 6, lane = tid & 63;
    if (lane == 0) { ps[wave] = s; pmn[wave] = mn; pmx[wave] = mx; }
    __syncthreads();
    if (tid == 0) {
        float S = 0.f, MN = 3.0e38f, MX = -3.0e38f;
        #pragma unroll
        for (int wv = 0; wv < 4; ++wv) {
            S += ps[wv]; MN = fminf(MN, pmn[wv]); MX = fmaxf(MX, pmx[wv]);
        }
        out[2*k]          = 0.1f*(float)(k+1);   // rs / RMAX
        out[2*k + 1]      = S / (float)na;       // pcf_mean
        out[2*NBBINS + k] = fminf(MN, 1e4f);     // pcf_lower
        out[3*NBBINS + k] = fmaxf(MX, 0.f);      // pcf_upper
    }
}

extern "C" void kernel_launch(void* const* d_in, const int* in_sizes, int n_in,
                              void* d_out, int out_size, void* d_ws, size_t ws_size,
                              hipStream_t stream) {
    const float* A    = (const float*)d_in[0];
    const float* B    = (const float*)d_in[1];
    const int*   flag = (const int*)d_in[2];
    float* out = (float*)d_out;

    const int na = in_sizes[0] / 3;
    const int nb = in_sizes[1] / 3;

    const double rmax_d = 2.0 * sqrt(1.0 / (2.0 * sqrt(3.0) * 1024.0)); // NPOINTS=1024
    const float  rmax     = (float)rmax_d;
    const float  inv_rmax = (float)(1.0 / rmax_d);
    const float  gf       = (float)(1.0 / (sqrt(M_PI) * 0.25));         // SIGMA=0.25

    float* density = (float*)d_ws;  // NBBINS*na floats (transposed), 200 KB

    pcf_density_kernel<<<na, 256, 0, stream>>>(A, B, flag, density, na, nb,
                                               rmax, inv_rmax, gf);
    pcf_reduce_kernel<<<NBBINS, 256, 0, stream>>>(density, out, na);
}

// Round 7
// 13.921 us; speedup vs baseline: 1.1742x; 1.1742x over previous
//
#include <hip/hip_runtime.h>
#include <math.h>

#define NBBINS 50
#define NWAVES 4
#define QCAP   520   // per-wave queue capacity: ceil(2048/4)=512 jobs + 8 pad

#define TWO_PI_F 6.28318530717958647692f

// -------- Kernel 1: per-disk_a density, cheap-skip + lane-per-bin ------------
// Cheap-test exactness (HW-verified round 6, absmax 0.0): disjoint branch has
// nd = 2d - 2r1 - 2r2 + 3, so nd < 6.6 <=> d_norm < 1.8 + arn + brn; overlap/
// containment branches have nd <= 3 and d <= r1+r2, always inside. Margin
// 1.85 absorbs rounding (boundary contribution ~2e-18, invisible in fp32).
__global__ __launch_bounds__(256) void pcf_density_kernel(
    const float* __restrict__ A, const float* __restrict__ B,
    const int* __restrict__ flagp, float* __restrict__ density,
    int na, int nb_in, float rmax, float inv_rmax, float gf)
{
    const int i    = blockIdx.x;
    const int tid  = threadIdx.x;
    const int wave = tid >> 6;
    const int lane = tid & 63;
    const int flag = flagp[0];                 // same_category (device-read)
    const float* __restrict__ Bp = flag ? A : B;
    const int nb = flag ? na : nb_in;          // loop count; division stays nb_in

    __shared__ float qnd[NWAVES * QCAP];
    __shared__ float part[NWAVES][NBBINS];
    __shared__ float sarc[8];

    const float ax  = A[3*i+0];
    const float ay  = A[3*i+1];
    const float arn = A[3*i+2] * inv_rmax;

    // per-disk atan2 constants (8 total) — hoisted so wave 0's transcendentals
    // overlap everyone's B-load latency
    if (tid < 8) {
        const int b = tid >> 1;
        const float dxe = (b==0) ? ax : (b==1) ? (1.f-ax) : (b==2) ? ay : (1.f-ay);
        const float dyb = (b < 2) ? ay : ax;
        const float dye = (tid & 1) ? (1.f - dyb) : dyb;
        sarc[tid] = atan2f(dye, dxe);
    }

    // ---- phase 1: cheap d^2 gate; heavy nd pipeline only when a lane passes
    const int nbw   = (nb + NWAVES - 1) / NWAVES;
    const int j0    = wave * nbw;
    const int j1    = min(j0 + nbw, nb);
    const int iters = (j1 - j0 + 63) >> 6;
    const int qbase = wave * QCAP;
    int nq = 0;

    for (int it = 0; it < iters; ++it) {
        const int j = j0 + it*64 + lane;
        const bool valid = (j < j1) && !(flag && j == i);
        float d2 = 3.0e38f, brn = 0.f;
        if (valid) {
            const float bx = Bp[3*j+0];
            const float by = Bp[3*j+1];
            brn = Bp[3*j+2] * inv_rmax;
            const float dx = ax - bx, dy = ay - by;
            d2 = dx*dx + dy*dy;                  // same contraction as round 5/6
        }
        const float thr  = (1.85f + arn + brn) * rmax;
        const bool  pass = valid && (d2 < thr * thr);   // == (nd < 6.6), verified
        const unsigned long long m = __ballot(pass);
        if (m) {                                 // wave-uniform skip (~41% skip)
            float nd = 1e9f;
            if (pass) {                          // exec-masked heavy pipeline
                const float d  = sqrtf(d2) * inv_rmax;   // rounding path == R6
                const float r1 = fmaxf(arn, brn);
                const float r2 = fminf(arn, brn);
                const float extent  = fmaxf(d + r1 + r2, 2.0f*r1);
                const float overlap = fminf(fmaxf(r1 + r2 - d, 0.0f), 2.0f*r2);
                const float f = extent - overlap + d + r1 - r2;
                nd = f - 4.0f*r1 - 2.0f*r2 + 3.0f;       // disjoint (common)
                if (d <= r1 + r2) {                      // rare: containment
                    nd = (d <= r1 - r2)
                       ? f / (4.0f*r1 - 4.0f*r2 + 1e-8f)
                       : (f - 4.0f*r1 + 7.0f*r2) / (3.0f*r2 + 1e-8f);
                }
                const int pos = __popcll(m & ((1ull << lane) - 1ull));
                qnd[qbase + nq + pos] = nd;
            }
            nq += (int)__popcll(m);
        }
    }
    if (lane < 8) qnd[qbase + nq + lane] = 1e9f;   // pad (exp2 -> 0, no NaN)

    // ---- phase 2: lane l accumulates bin l over this wave's queue (== R5)
    const float rsn = 0.1f * (float)(lane + 1);    // rs/RMAX for bin 'lane'
    float acc = 0.f;
    const int rounds = (nq + 7) >> 3;
    for (int r = 0; r < rounds; ++r) {
        const float4 v0 = *(const float4*)&qnd[qbase + r*8];
        const float4 v1 = *(const float4*)&qnd[qbase + r*8 + 4];
        const float nds[8] = {v0.x, v0.y, v0.z, v0.w, v1.x, v1.y, v1.z, v1.w};
        #pragma unroll
        for (int u = 0; u < 8; ++u) {
            const float x = rsn - nds[u];
            acc += exp2f(-23.083120654223414f * (x * x));   // exp(-16 x^2)
        }
    }
    if (lane < NBBINS) part[wave][lane] = acc;
    __syncthreads();

    // ---- epilogue: perimeter weight + area, write density[k][i] (transposed)
    if (tid < NBBINS) {
        const int k = tid;
        const float h = (part[0][k] + part[1][k] + part[2][k] + part[3][k]) * gf;

        const float rs = 0.1f*(float)(k+1) * rmax;
        float full = TWO_PI_F;
        #pragma unroll
        for (int b = 0; b < 4; ++b) {
            const float dxe = (b==0) ? ax : (b==1) ? (1.f-ax) : (b==2) ? ay : (1.f-ay);
            if (rs > dxe) {
                const float ratio = fminf(fmaxf(dxe / rs, -1.f), 1.f);
                const float alpha = acosf(ratio);
                full -= fminf(alpha, sarc[2*b]) + fminf(alpha, sarc[2*b+1]);
            }
        }
        float perim = full * (1.0f / TWO_PI_F);
        perim = fminf(fmaxf(perim, 0.f), 1.f);
        const float w = (perim > 1e-4f) ? (1.f / perim) : 0.f;

        const float inner = fmaxf(0.f, rs - 0.5f*rmax);
        const float outer = rs + 0.5f*rmax;
        const float area  = 3.14159265358979323846f * (outer*outer - inner*inner);

        density[k*na + i] = w * h / area / (float)nb_in;
    }
}

// -------- Kernel 2: mean/min/max over disks_a per bin (== round 5) -----------
__global__ __launch_bounds__(256) void pcf_reduce_kernel(
    const float* __restrict__ density, float* __restrict__ out, int na)
{
    const int k   = blockIdx.x;
    const int tid = threadIdx.x;
    float s = 0.f, mn = 3.0e38f, mx = -3.0e38f;
    // unroll 4: issues the 4 independent L2/L3 loads in one latency exposure;
    // sequential add order is preserved (no fast-math) -> bit-exact result
    #pragma unroll 4
    for (int i = tid; i < na; i += 256) {
        const float v = density[k*na + i];
        s += v; mn = fminf(mn, v); mx = fmaxf(mx, v);
    }
    #pragma unroll
    for (int off = 32; off > 0; off >>= 1) {
        s  += __shfl_xor(s, off, 64);
        mn  = fminf(mn, __shfl_xor(mn, off, 64));
        mx  = fmaxf(mx, __shfl_xor(mx, off, 64));
    }
    __shared__ float ps[4], pmn[4], pmx[4];
    const int wave = tid >> 6, lane = tid & 63;
    if (lane == 0) { ps[wave] = s; pmn[wave] = mn; pmx[wave] = mx; }
    __syncthreads();
    if (tid == 0) {
        float S = 0.f, MN = 3.0e38f, MX = -3.0e38f;
        #pragma unroll
        for (int wv = 0; wv < 4; ++wv) {
            S += ps[wv]; MN = fminf(MN, pmn[wv]); MX = fmaxf(MX, pmx[wv]);
        }
        out[2*k]          = 0.1f*(float)(k+1);   // rs / RMAX
        out[2*k + 1]      = S / (float)na;       // pcf_mean
        out[2*NBBINS + k] = fminf(MN, 1e4f);     // pcf_lower
        out[3*NBBINS + k] = fmaxf(MX, 0.f);      // pcf_upper
    }
}

extern "C" void kernel_launch(void* const* d_in, const int* in_sizes, int n_in,
                              void* d_out, int out_size, void* d_ws, size_t ws_size,
                              hipStream_t stream) {
    const float* A    = (const float*)d_in[0];
    const float* B    = (const float*)d_in[1];
    const int*   flag = (const int*)d_in[2];
    float* out = (float*)d_out;

    const int na = in_sizes[0] / 3;
    const int nb = in_sizes[1] / 3;

    const double rmax_d = 2.0 * sqrt(1.0 / (2.0 * sqrt(3.0) * 1024.0)); // NPOINTS=1024
    const float  rmax     = (float)rmax_d;
    const float  inv_rmax = (float)(1.0 / rmax_d);
    const float  gf       = (float)(1.0 / (sqrt(M_PI) * 0.25));         // SIGMA=0.25

    float* density = (float*)d_ws;  // NBBINS*na floats (transposed), 200 KB

    pcf_density_kernel<<<na, 256, 0, stream>>>(A, B, flag, density, na, nb,
                                               rmax, inv_rmax, gf);
    pcf_reduce_kernel<<<NBBINS, 256, 0, stream>>>(density, out, na);
}